// Round 11
// baseline (217.111 us; speedup 1.0000x reference)
//
#include <hip/hip_runtime.h>
#include <hip/hip_bf16.h>

// Fused MHA block: qkv proj -> flash attention -> out proj.
// All matmuls in bf16 MFMA (16x16x32), fp32 accumulate, exp2-domain softmax.
// Workspace layout (bytes):
//   [0,8M)   xb   : x cast to bf16           [4096][1024]
//   [8,14M)  wqb  : qkv_w bf16               [3072][1024]
//   [14,16M) pwb  : proj_w bf16              [1024][1024]
//   [16,24M) Qb   : Q*0.125*log2e bf16       [(b*16+h)*2048+n][64]
//   [24,32M) Kb   : K bf16 per head          [(b*16+h)*2048+n][64]
//   [32,40M) Vt   : V bf16 transposed        [(b*16+h)*64+hd][2048]
//   [40,48M) Ob   : attention out bf16       [b*2048+n][1024]
//
// Journal (perf-critical decisions):
//  - GEMMs: 1-phase 16KB LDS (m97 structure). Round 6's 2-phase dbuf (32KB)
//    lost ~16us (residency halved; m132's lesson). Do not re-add.
//  - k_attn: K AND V must be LDS-staged via global_load_lds. Round 7 read V
//    direct from global/L2: 73.7 -> 164.6us. Do not re-try.
//  - f2bf bit-twiddle for weights/activations, NOT v_cvt_pk_bf16_f32
//    (round 4: absmax 4.9e-4 -> 6.8e-3; hw cvt_pk is not RNE).
//  - P-tile pack: round-half-up (r8: neutral time, neutral absmax — keep).
//  - r9: 32 q-rows/wave (2 m-halves): 74.4 -> 63.4us. Keep.
//  - r10 FAILED: Vt LDS->global copy used uint2 (8B) with 16B stride — half
//    of Vt unwritten (absmax 3.4e-2). r11 fixes to uint4. 16B copy widths
//    must match 8-short strides.

#define DEV __device__ __forceinline__

typedef __attribute__((ext_vector_type(8))) __bf16 bf16x8;
typedef __attribute__((ext_vector_type(4))) float f32x4;

static DEV unsigned short f2bf(float f) {
  unsigned u = __builtin_bit_cast(unsigned, f);
  u += 0x7FFFu + ((u >> 16) & 1u);   // RNE
  return (unsigned short)(u >> 16);
}

// pair-pack f32->bf16, round-half-up: cheap and unbiased (ties-only deviation
// from RNE). Used for P tile and Vt pack.
static DEV unsigned pkhalfup(float lo, float hi) {
  unsigned a = __builtin_bit_cast(unsigned, lo) + 0x8000u;
  unsigned b = __builtin_bit_cast(unsigned, hi) + 0x8000u;
  return (a >> 16) | (b & 0xFFFF0000u);
}

static DEV float fexp2(float x) {
#if __has_builtin(__builtin_amdgcn_exp2f)
  return __builtin_amdgcn_exp2f(x);   // v_exp_f32 is 2^x
#else
  return __expf(x * 0.69314718055994531f);
#endif
}

static DEV float max3(float a, float b, float c) {
  return fmaxf(fmaxf(a, b), c);       // clang fuses to v_max3_f32
}

static DEV void gld16(const void* g, void* l) {
  __builtin_amdgcn_global_load_lds(
      (const __attribute__((address_space(1))) unsigned int*)g,
      (__attribute__((address_space(3))) unsigned int*)l, 16, 0, 0);
}

static DEV f32x4 mfma16(bf16x8 a, bf16x8 b, f32x4 c) {
  return __builtin_amdgcn_mfma_f32_16x16x32_bf16(a, b, c, 0, 0, 0);
}

// ---------------- fused fp32 -> bf16 convert (x | qkv_w | proj_w) ----------
__global__ void k_conv(const float* __restrict__ x, const float* __restrict__ qw,
                       const float* __restrict__ pw, unsigned short* __restrict__ xb,
                       unsigned short* __restrict__ wqb, unsigned short* __restrict__ pwb) {
  int b = blockIdx.x;
  const float* s;
  unsigned short* d;
  int base;
  if (b < 4096)      { s = x;  d = xb;  base = b; }
  else if (b < 7168) { s = qw; d = wqb; base = b - 4096; }
  else               { s = pw; d = pwb; base = b - 7168; }
  int i = (base * 256 + threadIdx.x) * 4;
  float4 v = *reinterpret_cast<const float4*>(s + i);
  union { unsigned short h[4]; uint2 u; } cv;
  cv.h[0] = f2bf(v.x); cv.h[1] = f2bf(v.y); cv.h[2] = f2bf(v.z); cv.h[3] = f2bf(v.w);
  *reinterpret_cast<uint2*>(d + i) = cv.u;
}

// ---------------- shared GEMM tile compute (128x128, 4 waves 2x2) ----------
static DEV void gemm_tile(const unsigned short* __restrict__ Asb,
                          const unsigned short* __restrict__ Bsb,
                          int wm, int wn, int fr, int fg, f32x4 (&acc)[4][4]) {
  bf16x8 af[4], bw[4];
#pragma unroll
  for (int m = 0; m < 4; ++m)
    af[m] = *reinterpret_cast<const bf16x8*>(Asb + (wm * 64 + m * 16 + fr) * 32 + fg * 8);
#pragma unroll
  for (int n = 0; n < 4; ++n)
    bw[n] = *reinterpret_cast<const bf16x8*>(Bsb + (wn * 64 + n * 16 + fr) * 32 + fg * 8);
#pragma unroll
  for (int m = 0; m < 4; ++m)
#pragma unroll
    for (int n = 0; n < 4; ++n)
      acc[m][n] = mfma16(af[m], bw[n], acc[m][n]);
}

// 1-phase staging (m97 structure): 16KB LDS, relies on multi-block TLP.
#define QSTAGE(k0)                                                            \
  {                                                                           \
    _Pragma("unroll")                                                         \
    for (int c = 0; c < 2; ++c) {                                             \
      int bi = c * 4096 + wid * 1024 + lane * 16;                             \
      int row = bi >> 6, ce = (bi & 63) >> 1;                                 \
      gld16(gA + (size_t)row * K + (k0) + ce, As + c * 2048 + wid * 512);     \
      gld16(gW + (size_t)row * K + (k0) + ce, Bs + c * 2048 + wid * 512);     \
    }                                                                         \
  }

// ---------------- QKV GEMM: C[4096][3072] = xb @ wqb^T + bias --------------
// 1D grid 768, bijective XCD swizzle; vid%24=bn, vid/24=bm so consecutive
// vids share an A-panel (L2-resident) while sweeping B (T1 mechanism).
__global__ __launch_bounds__(256) void k_qkv(
    const unsigned short* __restrict__ A, const unsigned short* __restrict__ W,
    const float* __restrict__ bias, unsigned short* __restrict__ Qb,
    unsigned short* __restrict__ Kb, unsigned short* __restrict__ Vt) {
  const int K = 1024;
  __shared__ __align__(16) unsigned short smem[8704];  // As|Bs (16KB) ∪ vxp
  unsigned short* As = smem;
  unsigned short* Bs = smem + 4096;
  const int tid = threadIdx.x, lane = tid & 63, wid = tid >> 6;
  const int wm = wid >> 1, wn = wid & 1, fr = lane & 15, fg = lane >> 4;
  const int vid = (int)(blockIdx.x & 7) * 96 + (int)(blockIdx.x >> 3);
  const size_t bm = vid / 24, bn = vid % 24;
  const unsigned short* gA = A + bm * 128 * K;
  const unsigned short* gW = W + bn * 128 * K;
  f32x4 acc[4][4] = {};
  for (int k0 = 0; k0 < K; k0 += 32) {
    QSTAGE(k0);
    __syncthreads();
    gemm_tile(As, Bs, wm, wn, fr, fg, acc);
    __syncthreads();
  }
  const float QSCALE = 0.18033688011112043f;  // 0.125 * log2(e)
  float bv[4];
#pragma unroll
  for (int n = 0; n < 4; ++n) bv[n] = bias[bn * 128 + wn * 64 + n * 16 + fr];
  if (bn < 16) {
    // Q / K: per-block uniform type (bn<8 -> Q, else K); semi-coalesced
#pragma unroll
    for (int m = 0; m < 4; ++m)
#pragma unroll
      for (int n = 0; n < 4; ++n) {
        int f = (int)bn * 128 + wn * 64 + n * 16 + fr;
        int t = f >> 10, d = f & 1023, h = d >> 6, hd = d & 63;
        int token0 = (int)bm * 128 + wm * 64 + m * 16 + fg * 4;  // r adds 0..3
        int b_ = token0 >> 11, nn0 = token0 & 2047;
        size_t bh = (size_t)(b_ * 16 + h);
        float v0 = acc[m][n][0] + bv[n], v1 = acc[m][n][1] + bv[n];
        float v2 = acc[m][n][2] + bv[n], v3 = acc[m][n][3] + bv[n];
        if (t == 0) {
          unsigned short* q = Qb + (bh * 2048 + nn0) * 64 + hd;
          q[0] = f2bf(v0 * QSCALE); q[64] = f2bf(v1 * QSCALE);
          q[128] = f2bf(v2 * QSCALE); q[192] = f2bf(v3 * QSCALE);
        } else {
          unsigned short* k = Kb + (bh * 2048 + nn0) * 64 + hd;
          k[0] = f2bf(v0); k[64] = f2bf(v1); k[128] = f2bf(v2); k[192] = f2bf(v3);
        }
      }
  } else {
    // V: transpose through LDS (vxp[64][136], padded) -> coalesced Vt stores.
    // r11 FIX: copies are uint4 (16B = 8 shorts) matching the j*8-short
    // stride; r10's uint2 left half of Vt unwritten.
    unsigned short* vxp = smem;
    const int d0 = ((int)bn - 16) * 128;
    const int token0 = (int)bm * 128;
    const int b_ = token0 >> 11, nnb = token0 & 2047;
    const int row = tid >> 2, qr = tid & 3;
#pragma unroll
    for (int phase = 0; phase < 2; ++phase) {
      __syncthreads();   // previous-phase reads (or K-loop) complete
      if (wn == phase) {
#pragma unroll
        for (int m = 0; m < 4; ++m)
#pragma unroll
          for (int n = 0; n < 4; ++n) {
            int fl = n * 16 + fr;                      // f_local within phase
            int tok = wm * 64 + m * 16 + fg * 4;       // +r 0..3
            float v0 = acc[m][n][0] + bv[n], v1 = acc[m][n][1] + bv[n];
            float v2 = acc[m][n][2] + bv[n], v3 = acc[m][n][3] + bv[n];
            uint2 pk;
            pk.x = pkhalfup(v0, v1);
            pk.y = pkhalfup(v2, v3);
            *reinterpret_cast<uint2*>(&vxp[fl * 136 + tok]) = pk;
          }
      }
      __syncthreads();
      int d = d0 + phase * 64 + row;
      int h = d >> 6, hd = d & 63;
      unsigned short* dst =
          Vt + ((size_t)(b_ * 16 + h) * 64 + hd) * 2048 + nnb + qr * 32;
      const unsigned short* src = &vxp[row * 136 + qr * 32];
#pragma unroll
      for (int j = 0; j < 4; ++j)
        *reinterpret_cast<uint4*>(dst + j * 8) =
            *reinterpret_cast<const uint4*>(src + j * 8);
    }
  }
}

// ---------------- Flash attention -----------------------------------------
// grid 1024 = (b,h)=32 x 32 q-tiles of 64; 2 waves x 32 q-rows (2 m-halves);
// KV tile 64; 4 blocks/CU (36KB LDS). Swapped QK^T; exp2 softmax + defer-max;
// K/V staged via global_load_lds (XOR-swizzle, static 2-tile dbuf); K/V frags
// serve both m-halves; setprio around MFMA clusters.
static DEV void attn_tile(const unsigned short* __restrict__ Ksb,
                          const unsigned short* __restrict__ Vsb,
                          unsigned short* __restrict__ pw,
                          const bf16x8 (&qf)[2][2], int fr, int fg,
                          const int* kcol, const int* pcol,
                          f32x4 (&accO)[2][4], float (&mrow)[2],
                          float (&lpart)[2]) {
  const int prow = fr * 64;
  f32x4 s[2][4] = {};
  __builtin_amdgcn_s_setprio(1);
#pragma unroll
  for (int nf = 0; nf < 4; ++nf)
#pragma unroll
    for (int ks = 0; ks < 2; ++ks) {
      bf16x8 kf = *reinterpret_cast<const bf16x8*>(&Ksb[(nf * 16 + fr) * 64 + kcol[ks]]);
      s[0][nf] = mfma16(kf, qf[0][ks], s[0][nf]);
      s[1][nf] = mfma16(kf, qf[1][ks], s[1][nf]);
    }
  __builtin_amdgcn_s_setprio(0);
  bf16x8 vf[2][4];
#pragma unroll
  for (int ks = 0; ks < 2; ++ks)
#pragma unroll
    for (int df = 0; df < 4; ++df)
      vf[ks][df] = *reinterpret_cast<const bf16x8*>(&Vsb[(df * 16 + fr) * 64 + kcol[ks]]);
#pragma unroll
  for (int m = 0; m < 2; ++m) {
    float m0 = max3(s[m][0][0], s[m][0][1], s[m][0][2]);
    float m1 = max3(s[m][0][3], s[m][1][0], s[m][1][1]);
    float m2 = max3(s[m][1][2], s[m][1][3], s[m][2][0]);
    float m3 = max3(s[m][2][1], s[m][2][2], s[m][2][3]);
    float m4 = max3(s[m][3][0], s[m][3][1], s[m][3][2]);
    float mymax = fmaxf(max3(m0, m1, m2), max3(m3, m4, s[m][3][3]));
    if (!__all(mymax <= mrow[m] + 8.0f)) {   // defer-max: rare path
      float pmax = fmaxf(mymax, __shfl_xor(mymax, 16));
      pmax = fmaxf(pmax, __shfl_xor(pmax, 32));
      float mnew = fmaxf(mrow[m], pmax);
      float sc = fexp2(mrow[m] - mnew);
      mrow[m] = mnew;
      lpart[m] *= sc;
      float scq[4];
#pragma unroll
      for (int r = 0; r < 4; ++r) scq[r] = __shfl(sc, fg * 4 + r);
#pragma unroll
      for (int df = 0; df < 4; ++df)
#pragma unroll
        for (int r = 0; r < 4; ++r) accO[m][df][r] *= scq[r];
    }
    float rsn[4];
#pragma unroll
    for (int nf = 0; nf < 4; ++nf) {
      float p0 = fexp2(s[m][nf][0] - mrow[m]), p1 = fexp2(s[m][nf][1] - mrow[m]);
      float p2 = fexp2(s[m][nf][2] - mrow[m]), p3 = fexp2(s[m][nf][3] - mrow[m]);
      uint2 pk;
      pk.x = pkhalfup(p0, p1);
      pk.y = pkhalfup(p2, p3);
      rsn[nf] = (p0 + p1) + (p2 + p3);
      *reinterpret_cast<uint2*>(&pw[prow + pcol[nf]]) = pk;
    }
    lpart[m] += (rsn[0] + rsn[1]) + (rsn[2] + rsn[3]);
    bf16x8 pf[2];
#pragma unroll
    for (int ks = 0; ks < 2; ++ks)
      pf[ks] = *reinterpret_cast<const bf16x8*>(&pw[prow + kcol[ks]]);
    __builtin_amdgcn_s_setprio(1);
#pragma unroll
    for (int df = 0; df < 4; ++df)
#pragma unroll
      for (int ks = 0; ks < 2; ++ks)
        accO[m][df] = mfma16(pf[ks], vf[ks][df], accO[m][df]);
    __builtin_amdgcn_s_setprio(0);
  }
}

__global__ __launch_bounds__(128) void k_attn(
    const unsigned short* __restrict__ Qb, const unsigned short* __restrict__ Kb,
    const unsigned short* __restrict__ Vt, unsigned short* __restrict__ Ob) {
  __shared__ __align__(16) unsigned short Ks0[64 * 64], Ks1[64 * 64];
  __shared__ __align__(16) unsigned short Vs0[64 * 64], Vs1[64 * 64];
  __shared__ __align__(16) unsigned short p_lds[2][16 * 64];  // wave-private
  const int tid = threadIdx.x, lane = tid & 63, w = tid >> 6;  // w in {0,1}
  const int fr = lane & 15, fg = lane >> 4;
  // bijective XCD swizzle: 1024 blocks, each XCD gets 128 consecutive ids
  // = 4 heads' K/V (2MB, fits 4MB L2).
  const int bid = (int)(blockIdx.x & 7) * 128 + (int)(blockIdx.x >> 3);
  const int qt = bid & 31, bh = bid >> 5;
  const unsigned short* Qp = Qb + ((size_t)bh * 2048 + qt * 64 + w * 32) * 64;
  const unsigned short* Kp = Kb + (size_t)bh * 2048 * 64;
  const unsigned short* Vp = Vt + (size_t)bh * 64 * 2048;
  unsigned short* pw = &p_lds[w][0];

  // hoisted swizzle offsets (loop-invariant per lane)
  int kcol[2], pcol[4];
#pragma unroll
  for (int ks = 0; ks < 2; ++ks) kcol[ks] = ((ks * 4 + fg) ^ (fr & 7)) * 8;
#pragma unroll
  for (int nf = 0; nf < 4; ++nf)
    pcol[nf] = (((2 * nf + (fg >> 1)) ^ (fr & 7)) * 8) + (fg & 1) * 4;

  const int crow0 = w * 32 + (lane >> 3);  // staging row; j adds 8
  bf16x8 qf[2][2];
#pragma unroll
  for (int m = 0; m < 2; ++m)
#pragma unroll
    for (int ks = 0; ks < 2; ++ks)
      qf[m][ks] = *reinterpret_cast<const bf16x8*>(
          Qp + (m * 16 + fr) * 64 + ks * 32 + fg * 8);

  f32x4 accO[2][4] = {};
  float mrow[2] = {-1e30f, -1e30f}, lpart[2] = {0.f, 0.f};

#define STAGE(KDST, VDST, kti)                                                \
  {                                                                           \
    const unsigned short* Kt_ = Kp + (kti) * 64 * 64;                         \
    _Pragma("unroll")                                                         \
    for (int j = 0; j < 4; ++j) {                                             \
      int cr = crow0 + j * 8;                                                 \
      int cs = (lane & 7) ^ (cr & 7);                                         \
      gld16(Kt_ + cr * 64 + cs * 8, (KDST) + (w * 4 + j) * 512);              \
      gld16(Vp + (size_t)cr * 2048 + (kti) * 64 + cs * 8,                     \
            (VDST) + (w * 4 + j) * 512);                                      \
    }                                                                         \
  }

  STAGE(Ks0, Vs0, 0);
  STAGE(Ks1, Vs1, 1);
  __syncthreads();
  for (int i = 0; i < 16; ++i) {
    attn_tile(Ks0, Vs0, pw, qf, fr, fg, kcol, pcol, accO, mrow, lpart);
    __syncthreads();
    if (i < 15) STAGE(Ks0, Vs0, 2 * i + 2);
    attn_tile(Ks1, Vs1, pw, qf, fr, fg, kcol, pcol, accO, mrow, lpart);
    __syncthreads();
    if (i < 15) STAGE(Ks1, Vs1, 2 * i + 3);
  }
#undef STAGE
  // epilogue: O[q][d], q = m*16 + fg*4 + r, d = df*16 + fr; l at lane q=fr
  const int b_ = bh >> 4, h = bh & 15;
#pragma unroll
  for (int m = 0; m < 2; ++m) {
    float lrow = lpart[m];
    lrow += __shfl_xor(lrow, 16);
    lrow += __shfl_xor(lrow, 32);
    float linv = 1.f / lrow;
    float lq[4];
#pragma unroll
    for (int r = 0; r < 4; ++r) lq[r] = __shfl(linv, fg * 4 + r);
#pragma unroll
    for (int df = 0; df < 4; ++df)
#pragma unroll
      for (int r = 0; r < 4; ++r) {
        int nn = qt * 64 + w * 32 + m * 16 + fg * 4 + r;
        int d = df * 16 + fr;
        Ob[(size_t)(b_ * 2048 + nn) * 1024 + h * 64 + d] =
            f2bf(accO[m][df][r] * lq[r]);
      }
  }
}

// ---------------- Proj GEMM: out[4096][1024] = Ob @ pwb^T + bias (fp32 out) -
// 1D grid 256, XCD swizzle: vid%8=bn, vid/8=bm (A-panel reuse, B L2-resident).
__global__ __launch_bounds__(256) void k_proj(
    const unsigned short* __restrict__ A, const unsigned short* __restrict__ W,
    const float* __restrict__ bias, float* __restrict__ out) {
  const int K = 1024;
  __shared__ __align__(16) unsigned short As[128 * 32], Bs[128 * 32];
  const int tid = threadIdx.x, lane = tid & 63, wid = tid >> 6;
  const int wm = wid >> 1, wn = wid & 1, fr = lane & 15, fg = lane >> 4;
  const int vid = (int)(blockIdx.x & 7) * 32 + (int)(blockIdx.x >> 3);
  const size_t bm = vid >> 3, bn = vid & 7;
  const unsigned short* gA = A + bm * 128 * K;
  const unsigned short* gW = W + bn * 128 * K;
  f32x4 acc[4][4] = {};
  for (int k0 = 0; k0 < K; k0 += 32) {
    QSTAGE(k0);
    __syncthreads();
    gemm_tile(As, Bs, wm, wn, fr, fg, acc);
    __syncthreads();
  }
  float bv[4];
#pragma unroll
  for (int n = 0; n < 4; ++n) bv[n] = bias[bn * 128 + wn * 64 + n * 16 + fr];
#pragma unroll
  for (int m = 0; m < 4; ++m)
#pragma unroll
    for (int n = 0; n < 4; ++n)
#pragma unroll
      for (int r = 0; r < 4; ++r) {
        size_t token = bm * 128 + wm * 64 + m * 16 + fg * 4 + r;
        int f = (int)bn * 128 + wn * 64 + n * 16 + fr;
        out[token * 1024 + f] = acc[m][n][r] + bv[n];
      }
}

extern "C" void kernel_launch(void* const* d_in, const int* in_sizes, int n_in,
                              void* d_out, int out_size, void* d_ws, size_t ws_size,
                              hipStream_t stream) {
  const float* x      = (const float*)d_in[0];
  const float* qkv_w  = (const float*)d_in[1];
  const float* qkv_b  = (const float*)d_in[2];
  const float* proj_w = (const float*)d_in[3];
  const float* proj_b = (const float*)d_in[4];
  float* out = (float*)d_out;
  char* ws = (char*)d_ws;
  unsigned short* xb  = (unsigned short*)(ws);
  unsigned short* wqb = (unsigned short*)(ws + (size_t)(8u << 20));
  unsigned short* pwb = (unsigned short*)(ws + (size_t)(14u << 20));
  unsigned short* Qb  = (unsigned short*)(ws + (size_t)(16u << 20));
  unsigned short* Kb  = (unsigned short*)(ws + (size_t)(24u << 20));
  unsigned short* Vt  = (unsigned short*)(ws + (size_t)(32u << 20));
  unsigned short* Ob  = (unsigned short*)(ws + (size_t)(40u << 20));

  k_conv<<<8192, 256, 0, stream>>>(x, qkv_w, proj_w, xb, wqb, pwb);
  k_qkv<<<768, 256, 0, stream>>>(xb, wqb, qkv_b, Qb, Kb, Vt);
  k_attn<<<1024, 128, 0, stream>>>(Qb, Kb, Vt, Ob);
  k_proj<<<256, 256, 0, stream>>>(Ob, pwb, proj_b, out);
}

// Round 12
// 192.941 us; speedup vs baseline: 1.1253x; 1.1253x over previous
//
#include <hip/hip_runtime.h>
#include <hip/hip_bf16.h>

// Fused MHA block: qkv proj -> flash attention -> out proj.
// All matmuls in bf16 MFMA (16x16x32), fp32 accumulate, exp2-domain softmax.
// Workspace layout (bytes):
//   [0,8M)   xb   : x cast to bf16           [4096][1024]
//   [8,14M)  wqb  : qkv_w bf16               [3072][1024]
//   [14,16M) pwb  : proj_w bf16              [1024][1024]
//   [16,24M) Qb   : Q*0.125*log2e bf16       [(b*16+h)*2048+n][64]
//   [24,32M) Kb   : K bf16 per head          [(b*16+h)*2048+n][64]
//   [32,40M) Vt   : V bf16 transposed        [(b*16+h)*64+hd][2048]
//   [40,48M) Ob   : attention out bf16       [b*2048+n][1024]
//
// Journal (perf-critical decisions):
//  - GEMMs: 1-phase 16KB LDS (m97 structure). r6 2-phase dbuf (32KB) lost
//    ~16us (residency halved; m132). Do not re-add.
//  - k_qkv grid must keep B-panel inner-reused (2D x-major). r10/r11's 1D
//    bn-inner swizzle = 24 B-panels/XCD epoch = 6MB > 4MB L2 thrash, and the
//    Vt LDS-transpose epilogue added barriers: rest 131 -> 146.5us. Reverted.
//  - k_attn: K AND V must be LDS-staged via global_load_lds (r7 direct-L2 V:
//    73.7 -> 164.6us). 4-wave blocks + 32 q-rows/wave (r9) beat 2-wave
//    split (r11: 63.4 -> 70.6us). This r9 attn form is the keeper.
//  - f2bf bit-twiddle, NOT v_cvt_pk_bf16_f32 (r4: absmax 4.9e-4 -> 6.8e-3).
//  - P-tile pack: round-half-up (r8: neutral time, neutral absmax — keep).

#define DEV __device__ __forceinline__

typedef __attribute__((ext_vector_type(8))) __bf16 bf16x8;
typedef __attribute__((ext_vector_type(4))) float f32x4;

static DEV unsigned short f2bf(float f) {
  unsigned u = __builtin_bit_cast(unsigned, f);
  u += 0x7FFFu + ((u >> 16) & 1u);   // RNE
  return (unsigned short)(u >> 16);
}

// pair-pack f32->bf16, round-half-up: cheap and unbiased (ties-only deviation
// from RNE). Used ONLY for the P tile.
static DEV unsigned pkhalfup(float lo, float hi) {
  unsigned a = __builtin_bit_cast(unsigned, lo) + 0x8000u;
  unsigned b = __builtin_bit_cast(unsigned, hi) + 0x8000u;
  return (a >> 16) | (b & 0xFFFF0000u);
}

static DEV float fexp2(float x) {
#if __has_builtin(__builtin_amdgcn_exp2f)
  return __builtin_amdgcn_exp2f(x);   // v_exp_f32 is 2^x
#else
  return __expf(x * 0.69314718055994531f);
#endif
}

static DEV float max3(float a, float b, float c) {
  return fmaxf(fmaxf(a, b), c);       // clang fuses to v_max3_f32
}

static DEV void gld16(const void* g, void* l) {
  __builtin_amdgcn_global_load_lds(
      (const __attribute__((address_space(1))) unsigned int*)g,
      (__attribute__((address_space(3))) unsigned int*)l, 16, 0, 0);
}

static DEV f32x4 mfma16(bf16x8 a, bf16x8 b, f32x4 c) {
  return __builtin_amdgcn_mfma_f32_16x16x32_bf16(a, b, c, 0, 0, 0);
}

// ---------------- fused fp32 -> bf16 convert (x | qkv_w | proj_w) ----------
__global__ void k_conv(const float* __restrict__ x, const float* __restrict__ qw,
                       const float* __restrict__ pw, unsigned short* __restrict__ xb,
                       unsigned short* __restrict__ wqb, unsigned short* __restrict__ pwb) {
  int b = blockIdx.x;
  const float* s;
  unsigned short* d;
  int base;
  if (b < 4096)      { s = x;  d = xb;  base = b; }
  else if (b < 7168) { s = qw; d = wqb; base = b - 4096; }
  else               { s = pw; d = pwb; base = b - 7168; }
  int i = (base * 256 + threadIdx.x) * 4;
  float4 v = *reinterpret_cast<const float4*>(s + i);
  union { unsigned short h[4]; uint2 u; } cv;
  cv.h[0] = f2bf(v.x); cv.h[1] = f2bf(v.y); cv.h[2] = f2bf(v.z); cv.h[3] = f2bf(v.w);
  *reinterpret_cast<uint2*>(d + i) = cv.u;
}

// ---------------- shared GEMM tile compute (128x128, 4 waves 2x2) ----------
static DEV void gemm_tile(const unsigned short* __restrict__ Asb,
                          const unsigned short* __restrict__ Bsb,
                          int wm, int wn, int fr, int fg, f32x4 (&acc)[4][4]) {
  bf16x8 af[4], bw[4];
#pragma unroll
  for (int m = 0; m < 4; ++m)
    af[m] = *reinterpret_cast<const bf16x8*>(Asb + (wm * 64 + m * 16 + fr) * 32 + fg * 8);
#pragma unroll
  for (int n = 0; n < 4; ++n)
    bw[n] = *reinterpret_cast<const bf16x8*>(Bsb + (wn * 64 + n * 16 + fr) * 32 + fg * 8);
#pragma unroll
  for (int m = 0; m < 4; ++m)
#pragma unroll
    for (int n = 0; n < 4; ++n)
      acc[m][n] = mfma16(af[m], bw[n], acc[m][n]);
}

// 1-phase staging (m97 structure): 16KB LDS, relies on multi-block TLP.
#define QSTAGE(k0)                                                            \
  {                                                                           \
    _Pragma("unroll")                                                         \
    for (int c = 0; c < 2; ++c) {                                             \
      int bi = c * 4096 + wid * 1024 + lane * 16;                             \
      int row = bi >> 6, ce = (bi & 63) >> 1;                                 \
      gld16(gA + (size_t)row * K + (k0) + ce, As + c * 2048 + wid * 512);     \
      gld16(gW + (size_t)row * K + (k0) + ce, Bs + c * 2048 + wid * 512);     \
    }                                                                         \
  }

// ---------------- QKV GEMM: C[4096][3072] = xb @ wqb^T + bias --------------
__global__ __launch_bounds__(256) void k_qkv(
    const unsigned short* __restrict__ A, const unsigned short* __restrict__ W,
    const float* __restrict__ bias, unsigned short* __restrict__ Qb,
    unsigned short* __restrict__ Kb, unsigned short* __restrict__ Vt) {
  const int K = 1024;
  __shared__ __align__(16) unsigned short As[128 * 32], Bs[128 * 32];
  const int tid = threadIdx.x, lane = tid & 63, wid = tid >> 6;
  const int wm = wid >> 1, wn = wid & 1, fr = lane & 15, fg = lane >> 4;
  const size_t bm = blockIdx.x, bn = blockIdx.y;
  const unsigned short* gA = A + bm * 128 * K;
  const unsigned short* gW = W + bn * 128 * K;
  f32x4 acc[4][4] = {};
  for (int k0 = 0; k0 < K; k0 += 32) {
    QSTAGE(k0);
    __syncthreads();
    gemm_tile(As, Bs, wm, wn, fr, fg, acc);
    __syncthreads();
  }
  const float QSCALE = 0.18033688011112043f;  // 0.125 * log2(e)
  float bv[4];
#pragma unroll
  for (int n = 0; n < 4; ++n) bv[n] = bias[bn * 128 + wn * 64 + n * 16 + fr];
#pragma unroll
  for (int m = 0; m < 4; ++m)
#pragma unroll
    for (int n = 0; n < 4; ++n) {
      int f = (int)bn * 128 + wn * 64 + n * 16 + fr;
      int t = f >> 10, d = f & 1023, h = d >> 6, hd = d & 63;
      int token0 = (int)bm * 128 + wm * 64 + m * 16 + fg * 4;  // r adds 0..3
      int b_ = token0 >> 11, nn0 = token0 & 2047;
      size_t bh = (size_t)(b_ * 16 + h);
      float v0 = acc[m][n][0] + bv[n], v1 = acc[m][n][1] + bv[n];
      float v2 = acc[m][n][2] + bv[n], v3 = acc[m][n][3] + bv[n];
      if (t == 0) {
        unsigned short* q = Qb + (bh * 2048 + nn0) * 64 + hd;
        q[0] = f2bf(v0 * QSCALE); q[64] = f2bf(v1 * QSCALE);
        q[128] = f2bf(v2 * QSCALE); q[192] = f2bf(v3 * QSCALE);
      } else if (t == 1) {
        unsigned short* k = Kb + (bh * 2048 + nn0) * 64 + hd;
        k[0] = f2bf(v0); k[64] = f2bf(v1); k[128] = f2bf(v2); k[192] = f2bf(v3);
      } else {
        union { unsigned short h[4]; uint2 u; } pk;
        pk.h[0] = f2bf(v0); pk.h[1] = f2bf(v1);
        pk.h[2] = f2bf(v2); pk.h[3] = f2bf(v3);
        *reinterpret_cast<uint2*>(Vt + (bh * 64 + hd) * 2048 + nn0) = pk.u;
      }
    }
}

// ---------------- Flash attention -----------------------------------------
// grid 512 = (b,h)=32 x 16 q-tiles of 128; 4 waves x 32 q-rows (2 m-halves);
// KV tile 64. Swapped QK^T (S^T = mfma(K,Q)); exp2 softmax with defer-max;
// K/V staged to LDS via global_load_lds (XOR-swizzle, static 2-tile dbuf);
// K-frags and V-frags in reg serve BOTH m-halves (2x MFMA per LDS/barrier).
static DEV void attn_tile(const unsigned short* __restrict__ Ksb,
                          const unsigned short* __restrict__ Vsb,
                          unsigned short* __restrict__ pw,
                          const bf16x8 (&qf)[2][2], int fr, int fg,
                          const int* kcol, const int* pcol,
                          f32x4 (&accO)[2][4], float (&mrow)[2],
                          float (&lpart)[2]) {
  const int prow = fr * 64;
  f32x4 s[2][4] = {};
  __builtin_amdgcn_s_setprio(1);
#pragma unroll
  for (int nf = 0; nf < 4; ++nf)
#pragma unroll
    for (int ks = 0; ks < 2; ++ks) {
      bf16x8 kf = *reinterpret_cast<const bf16x8*>(&Ksb[(nf * 16 + fr) * 64 + kcol[ks]]);
      s[0][nf] = mfma16(kf, qf[0][ks], s[0][nf]);
      s[1][nf] = mfma16(kf, qf[1][ks], s[1][nf]);
    }
  __builtin_amdgcn_s_setprio(0);
  bf16x8 vf[2][4];
#pragma unroll
  for (int ks = 0; ks < 2; ++ks)
#pragma unroll
    for (int df = 0; df < 4; ++df)
      vf[ks][df] = *reinterpret_cast<const bf16x8*>(&Vsb[(df * 16 + fr) * 64 + kcol[ks]]);
#pragma unroll
  for (int m = 0; m < 2; ++m) {
    // row max over this lane's 16 scores (v_max3 tree)
    float m0 = max3(s[m][0][0], s[m][0][1], s[m][0][2]);
    float m1 = max3(s[m][0][3], s[m][1][0], s[m][1][1]);
    float m2 = max3(s[m][1][2], s[m][1][3], s[m][2][0]);
    float m3 = max3(s[m][2][1], s[m][2][2], s[m][2][3]);
    float m4 = max3(s[m][3][0], s[m][3][1], s[m][3][2]);
    float mymax = fmaxf(max3(m0, m1, m2), max3(m3, m4, s[m][3][3]));
    if (!__all(mymax <= mrow[m] + 8.0f)) {   // defer-max: rare path
      float pmax = fmaxf(mymax, __shfl_xor(mymax, 16));
      pmax = fmaxf(pmax, __shfl_xor(pmax, 32));
      float mnew = fmaxf(mrow[m], pmax);
      float sc = fexp2(mrow[m] - mnew);
      mrow[m] = mnew;
      lpart[m] *= sc;
      float scq[4];
#pragma unroll
      for (int r = 0; r < 4; ++r) scq[r] = __shfl(sc, fg * 4 + r);
#pragma unroll
      for (int df = 0; df < 4; ++df)
#pragma unroll
        for (int r = 0; r < 4; ++r) accO[m][df][r] *= scq[r];
    }
    float rsn[4];
#pragma unroll
    for (int nf = 0; nf < 4; ++nf) {
      float p0 = fexp2(s[m][nf][0] - mrow[m]), p1 = fexp2(s[m][nf][1] - mrow[m]);
      float p2 = fexp2(s[m][nf][2] - mrow[m]), p3 = fexp2(s[m][nf][3] - mrow[m]);
      uint2 pk;
      pk.x = pkhalfup(p0, p1);
      pk.y = pkhalfup(p2, p3);
      rsn[nf] = (p0 + p1) + (p2 + p3);
      *reinterpret_cast<uint2*>(&pw[prow + pcol[nf]]) = pk;
    }
    lpart[m] += (rsn[0] + rsn[1]) + (rsn[2] + rsn[3]);
    bf16x8 pf[2];
#pragma unroll
    for (int ks = 0; ks < 2; ++ks)
      pf[ks] = *reinterpret_cast<const bf16x8*>(&pw[prow + kcol[ks]]);
    __builtin_amdgcn_s_setprio(1);
#pragma unroll
    for (int df = 0; df < 4; ++df)
#pragma unroll
      for (int ks = 0; ks < 2; ++ks)
        accO[m][df] = mfma16(pf[ks], vf[ks][df], accO[m][df]);
    __builtin_amdgcn_s_setprio(0);
  }
}

__global__ __launch_bounds__(256) void k_attn(
    const unsigned short* __restrict__ Qb, const unsigned short* __restrict__ Kb,
    const unsigned short* __restrict__ Vt, unsigned short* __restrict__ Ob) {
  __shared__ __align__(16) unsigned short Ks0[64 * 64], Ks1[64 * 64];
  __shared__ __align__(16) unsigned short Vs0[64 * 64], Vs1[64 * 64];
  __shared__ __align__(16) unsigned short p_lds[4][16 * 64];  // wave-private,
  const int tid = threadIdx.x, lane = tid & 63, w = tid >> 6;  // reused per m
  const int fr = lane & 15, fg = lane >> 4;
  // bijective XCD swizzle: 512 blocks, each XCD gets 64 consecutive ids
  // = 4 heads' K/V (2MB, fits 4MB L2).
  const int bid = (int)(blockIdx.x & 7) * 64 + (int)(blockIdx.x >> 3);
  const int qt = bid & 15, bh = bid >> 4;
  const unsigned short* Qp = Qb + ((size_t)bh * 2048 + qt * 128 + w * 32) * 64;
  const unsigned short* Kp = Kb + (size_t)bh * 2048 * 64;
  const unsigned short* Vp = Vt + (size_t)bh * 64 * 2048;
  unsigned short* pw = &p_lds[w][0];

  // hoisted swizzle offsets (loop-invariant per lane)
  int kcol[2], pcol[4];
#pragma unroll
  for (int ks = 0; ks < 2; ++ks) kcol[ks] = ((ks * 4 + fg) ^ (fr & 7)) * 8;
#pragma unroll
  for (int nf = 0; nf < 4; ++nf)
    pcol[nf] = (((2 * nf + (fg >> 1)) ^ (fr & 7)) * 8) + (fg & 1) * 4;

  const int crow0 = w * 16 + (lane >> 3);  // staging row; j=1 adds 8
  bf16x8 qf[2][2];
#pragma unroll
  for (int m = 0; m < 2; ++m)
#pragma unroll
    for (int ks = 0; ks < 2; ++ks)
      qf[m][ks] = *reinterpret_cast<const bf16x8*>(
          Qp + (m * 16 + fr) * 64 + ks * 32 + fg * 8);

  f32x4 accO[2][4] = {};
  float mrow[2] = {-1e30f, -1e30f}, lpart[2] = {0.f, 0.f};

#define STAGE(KDST, VDST, kti)                                                \
  {                                                                           \
    const unsigned short* Kt_ = Kp + (kti) * 64 * 64;                         \
    _Pragma("unroll")                                                         \
    for (int j = 0; j < 2; ++j) {                                             \
      int cr = crow0 + j * 8;                                                 \
      int cs = (lane & 7) ^ (cr & 7);                                         \
      gld16(Kt_ + cr * 64 + cs * 8, (KDST) + (w * 2 + j) * 512);              \
      gld16(Vp + (size_t)cr * 2048 + (kti) * 64 + cs * 8,                     \
            (VDST) + (w * 2 + j) * 512);                                      \
    }                                                                         \
  }

  STAGE(Ks0, Vs0, 0);
  STAGE(Ks1, Vs1, 1);
  __syncthreads();
  for (int i = 0; i < 16; ++i) {
    attn_tile(Ks0, Vs0, pw, qf, fr, fg, kcol, pcol, accO, mrow, lpart);
    __syncthreads();
    if (i < 15) STAGE(Ks0, Vs0, 2 * i + 2);
    attn_tile(Ks1, Vs1, pw, qf, fr, fg, kcol, pcol, accO, mrow, lpart);
    __syncthreads();
    if (i < 15) STAGE(Ks1, Vs1, 2 * i + 3);
  }
#undef STAGE
  // epilogue: O[q][d], q = m*16 + fg*4 + r, d = df*16 + fr; l at lane q=fr
  const int b_ = bh >> 4, h = bh & 15;
#pragma unroll
  for (int m = 0; m < 2; ++m) {
    float lrow = lpart[m];
    lrow += __shfl_xor(lrow, 16);
    lrow += __shfl_xor(lrow, 32);
    float linv = 1.f / lrow;
    float lq[4];
#pragma unroll
    for (int r = 0; r < 4; ++r) lq[r] = __shfl(linv, fg * 4 + r);
#pragma unroll
    for (int df = 0; df < 4; ++df)
#pragma unroll
      for (int r = 0; r < 4; ++r) {
        int nn = qt * 128 + w * 32 + m * 16 + fg * 4 + r;
        int d = df * 16 + fr;
        Ob[(size_t)(b_ * 2048 + nn) * 1024 + h * 64 + d] =
            f2bf(accO[m][df][r] * lq[r]);
      }
  }
}

// ---------------- Proj GEMM: out[4096][1024] = Ob @ pwb^T + bias (fp32 out) -
// 1D grid 256, XCD swizzle: vid&7=bn, vid>>3=bm — per-XCD epoch keeps all 8
// B-panels (2MB) L2-resident while reusing the A-panel (r11-proven correct).
__global__ __launch_bounds__(256) void k_proj(
    const unsigned short* __restrict__ A, const unsigned short* __restrict__ W,
    const float* __restrict__ bias, float* __restrict__ out) {
  const int K = 1024;
  __shared__ __align__(16) unsigned short As[128 * 32], Bs[128 * 32];
  const int tid = threadIdx.x, lane = tid & 63, wid = tid >> 6;
  const int wm = wid >> 1, wn = wid & 1, fr = lane & 15, fg = lane >> 4;
  const int vid = (int)(blockIdx.x & 7) * 32 + (int)(blockIdx.x >> 3);
  const size_t bm = vid >> 3, bn = vid & 7;
  const unsigned short* gA = A + bm * 128 * K;
  const unsigned short* gW = W + bn * 128 * K;
  f32x4 acc[4][4] = {};
  for (int k0 = 0; k0 < K; k0 += 32) {
    QSTAGE(k0);
    __syncthreads();
    gemm_tile(As, Bs, wm, wn, fr, fg, acc);
    __syncthreads();
  }
  float bv[4];
#pragma unroll
  for (int n = 0; n < 4; ++n) bv[n] = bias[bn * 128 + wn * 64 + n * 16 + fr];
#pragma unroll
  for (int m = 0; m < 4; ++m)
#pragma unroll
    for (int n = 0; n < 4; ++n)
#pragma unroll
      for (int r = 0; r < 4; ++r) {
        size_t token = bm * 128 + wm * 64 + m * 16 + fg * 4 + r;
        int f = (int)bn * 128 + wn * 64 + n * 16 + fr;
        out[token * 1024 + f] = acc[m][n][r] + bv[n];
      }
}

extern "C" void kernel_launch(void* const* d_in, const int* in_sizes, int n_in,
                              void* d_out, int out_size, void* d_ws, size_t ws_size,
                              hipStream_t stream) {
  const float* x      = (const float*)d_in[0];
  const float* qkv_w  = (const float*)d_in[1];
  const float* qkv_b  = (const float*)d_in[2];
  const float* proj_w = (const float*)d_in[3];
  const float* proj_b = (const float*)d_in[4];
  float* out = (float*)d_out;
  char* ws = (char*)d_ws;
  unsigned short* xb  = (unsigned short*)(ws);
  unsigned short* wqb = (unsigned short*)(ws + (size_t)(8u << 20));
  unsigned short* pwb = (unsigned short*)(ws + (size_t)(14u << 20));
  unsigned short* Qb  = (unsigned short*)(ws + (size_t)(16u << 20));
  unsigned short* Kb  = (unsigned short*)(ws + (size_t)(24u << 20));
  unsigned short* Vt  = (unsigned short*)(ws + (size_t)(32u << 20));
  unsigned short* Ob  = (unsigned short*)(ws + (size_t)(40u << 20));

  k_conv<<<8192, 256, 0, stream>>>(x, qkv_w, proj_w, xb, wqb, pwb);
  k_qkv<<<dim3(32, 24), 256, 0, stream>>>(xb, wqb, qkv_b, Qb, Kb, Vt);
  k_attn<<<512, 256, 0, stream>>>(Qb, Kb, Vt, Ob);
  k_proj<<<256, 256, 0, stream>>>(Ob, pwb, proj_b, out);
}